// Round 15
// baseline (459.028 us; speedup 1.0000x reference)
//
#include <hip/hip_runtime.h>
#include <math.h>

// RBF mixture: out[i] = sum_m w_m * exp(-(x_i-mu_m)^T C_m (x_i-mu_m)), C_m = G_m G_m^T
// N=32768, M=2048, D=32.
// Round 15: MX-fp8 screen, executed right this time. r11 passed numerically
// but spilled in-loop (acc[8][4] + int8v frags > 256-reg cap) and broke the
// conflict-free LDS shape (paired 16B chunks). Fixes: acc[8][2] (64 AGPR,
// ~150 regs total, no spill at 2 waves/SIMD), 32-B-chunk XOR swizzle (the
// r3-r12-verified bf16 pattern at double width), SCREEN 160->125 (9-sigma
// margin; r11's 160 bloated survivor work by ~75us). 5 ksteps of K=128 via
// mfma_scale_f32_16x16x128_f8f6f4; B per-row e8m0 scale, A unit scale,
// c-term dropped from GEMM (screen vs th_m = SCREEN - mu^T C mu).

#define NN 32768
#define MM 2048
#define DDIM 32
#define KQ 640             // 528 tri + 32 cross + 80 zero pad = 5*128
#define ROWS 128
#define KSTEPS 5
#define SCREEN 125.0f
#define MCAP 2048
#define FCAP 1000000
#define FBLK 64

typedef __attribute__((ext_vector_type(4))) float floatx4;
typedef __attribute__((ext_vector_type(8))) int int8v;

__device__ __forceinline__ unsigned int to_bf16(float f) {
  union { float f; unsigned int u; } x; x.f = f;
  return (x.u + 0x7fffu + ((x.u >> 16) & 1u)) >> 16;
}

struct DFTab { unsigned char d[528]; unsigned char f[528]; };
constexpr DFTab make_df() {
  DFTab t{};
  int s = 0;
  for (int d = 0; d < 32; ++d)
    for (int f = d; f < 32; ++f) {
      t.d[s] = (unsigned char)d; t.f[s] = (unsigned char)f; ++s;
    }
  return t;
}
constexpr DFTab DFT = make_df();

// A[row][s]: tri products | cross x_d | zero pad (c-term NOT in GEMM)
__device__ __forceinline__ float slot_val(const float* v, int s) {
  if (s < 528) return v[DFT.d[s]] * v[DFT.f[s]];
  if (s < 560) return v[s - 528];
  return 0.f;
}

__device__ __forceinline__ void slot_df(int s, int* dd, int* ff) {
  int d = 0, b = 0;
  while (b + (DDIM - d) <= s) { b += DDIM - d; ++d; }
  *dd = d; *ff = d + (s - b);
}

// ---------------------------------------------------------------------------
// Kernel 1: fp8 B [M][KQ] (e4m3, per-row e8m0 scale in sB), th[M] =
// SCREEN - mu^T C mu. Also zeros acc/mcnt/fcount (fused memset).
// (Numerics verified in r11.)
// ---------------------------------------------------------------------------
__global__ __launch_bounds__(256) void build_b_kernel(
    const float* __restrict__ gamma, const float* __restrict__ means,
    unsigned char* __restrict__ Bm8, unsigned char* __restrict__ sB,
    float* __restrict__ th, double* __restrict__ acc,
    unsigned int* __restrict__ mcnt, unsigned int* __restrict__ fcount) {
  __shared__ float G[DDIM][DDIM + 1];
  __shared__ float C[DDIM][DDIM + 1];
  __shared__ float bv[DDIM];
  __shared__ float cc;
  __shared__ float rmax[4];
  const int m = blockIdx.x;
  const int t = threadIdx.x;
  if (t < 16) acc[m * 16 + t] = 0.0;
  if (t == 16) mcnt[m] = 0u;
  if (m == 0 && t == 17) *fcount = 0u;
  const float* g = gamma + (size_t)m * DDIM * DDIM;
  for (int l = t; l < DDIM * DDIM; l += 256) G[l >> 5][l & 31] = g[l];
  __syncthreads();
  const float* mu = means + m * DDIM;
  for (int l = t; l < DDIM * DDIM; l += 256) {
    int d = l >> 5, f = l & 31;
    float c = 0.f;
#pragma unroll
    for (int e = 0; e < DDIM; ++e) c += G[d][e] * G[f][e];
    C[d][f] = c;
  }
  __syncthreads();
  if (t < DDIM) {
    float b = 0.f;
#pragma unroll
    for (int f = 0; f < DDIM; ++f) b += C[t][f] * mu[f];
    bv[t] = b;
  }
  __syncthreads();
  if (t == 0) {
    float c = 0.f;
#pragma unroll
    for (int d = 0; d < DDIM; ++d) c += bv[d] * mu[d];
    cc = c;
  }
  __syncthreads();
  float vals[4];
  float lmax = 0.f;
  if (t < 140) {
#pragma unroll
    for (int q = 0; q < 4; ++q) {
      int s = t * 4 + q;
      float val;
      if (s < 528) {
        int d, f; slot_df(s, &d, &f);
        val = (d == f) ? C[d][d] : 2.f * C[d][f];
      } else if (s < 560) {
        val = -2.f * bv[s - 528];
      } else {
        val = 0.f;
      }
      vals[q] = val;
      lmax = fmaxf(lmax, fabsf(val));
    }
  }
  if (t < 4) rmax[t] = 0.f;
  __syncthreads();
  if (t < 140) {
    float wmax = lmax;
#pragma unroll
    for (int off = 32; off >= 1; off >>= 1)
      wmax = fmaxf(wmax, __shfl_down(wmax, off, 64));
    if ((t & 63) == 0) rmax[t >> 6] = wmax;
  }
  __syncthreads();
  __shared__ float sc_inv;
  if (t == 0) {
    float rm = fmaxf(fmaxf(rmax[0], rmax[1]), rmax[2]);
    int e = 0;
    while (rm > 448.f * (float)(1 << e) && e < 16) ++e;
    sc_inv = 1.f / (float)(1 << e);
    sB[m] = (unsigned char)(127 + e);
    th[m] = SCREEN - cc;
  }
  __syncthreads();
  if (t < 160) {
    unsigned int dw = 0;
    if (t < 140) {
      float si = sc_inv;
      int d0 = __builtin_amdgcn_cvt_pk_fp8_f32(vals[0] * si, vals[1] * si, 0, false);
      dw = (unsigned int)__builtin_amdgcn_cvt_pk_fp8_f32(vals[2] * si, vals[3] * si, d0, true);
    }
    *(unsigned int*)(Bm8 + (size_t)m * KQ + t * 4) = dw;
  }
}

// ---------------------------------------------------------------------------
// Exact scalar path (fallback list only).
// ---------------------------------------------------------------------------
__device__ __noinline__ double survivor_contrib(
    int m, const float* __restrict__ gamma, const float* __restrict__ means,
    const float* __restrict__ weights, const float* __restrict__ xrow) {
  const float* mu = means + m * DDIM;
  float v[DDIM];
#pragma unroll
  for (int d = 0; d < DDIM; ++d) v[d] = xrow[d] - mu[d];
  const float* g = gamma + (size_t)m * DDIM * DDIM;
  float Dex = 0.f;
  for (int e = 0; e < DDIM; ++e) {
    float y = 0.f;
#pragma unroll
    for (int d = 0; d < DDIM; ++d) y += g[d * DDIM + e] * v[d];
    Dex += y * y;
  }
  float e2 = -Dex * 1.44269504088896340736f;
  float kf = floorf(e2);
  float mant = exp2f(e2 - kf);
  return ldexp((double)(weights[m] * mant), (int)kf);
}

// ---------------------------------------------------------------------------
// Kernel 2: MX-fp8 MFMA screen. 512 thr (8 waves), 128-row fp8 A-tile in
// 80 KB dynamic LDS. Swizzle on 32-B chunks (20/row) in groups of 4:
// cs = (c&~3)|((c&3)^(r&3)) -- identical shape to the 0-conflict bf16
// pattern, each lane's 32-B frag = two ADJACENT b128 reads.
// Per kstep (K=128): per wave 4 B-b128 + 16 A-b128 + 16 mfma_scale.
// acc[8][2] = 64 AGPR; total regs ~150 -> no spill at the 256 cap.
// Wave w sweeps m-groups of 32: mq = ((g*8+w)+rot)&63, g=0..7.
// Frags: row=lane&15, k=quad*32..+31 (32 B). C/D: col=lane&15,
// row=quad*4+reg (shape-determined). Screen: acc < th[m].
// ---------------------------------------------------------------------------
__global__ __launch_bounds__(512, 1) void screen_kernel(
    const float* __restrict__ x, const unsigned char* __restrict__ Bm8,
    const unsigned char* __restrict__ sB, const float* __restrict__ th,
    unsigned int* __restrict__ mcnt, unsigned short* __restrict__ mlist,
    unsigned int* __restrict__ flist, unsigned int* __restrict__ fcount) {
  extern __shared__ __align__(16) unsigned char As[];    // ROWS * KQ bytes
  const int t = threadIdx.x;
  const int i0 = blockIdx.x * ROWS;
  const int lane = t & 63, w = t >> 6;                   // w in [0,8)
  const int lrow = lane & 15, quad = lane >> 4;
  const int rot = blockIdx.x & 63;

  // ---- generate fp8 A tile: row r (128), quarter j (4) x 5 chunks of 32B ----
  {
    const int r = t >> 2, j = t & 3;
    float v[DDIM];
#pragma unroll
    for (int q = 0; q < 8; ++q)
      *(floatx4*)&v[q * 4] = *(const floatx4*)(x + (size_t)(i0 + r) * DDIM + q * 4);
#pragma unroll
    for (int jj = 0; jj < 4; ++jj) {
      if (j == jj) {
#pragma unroll
        for (int cc2 = 0; cc2 < 5; ++cc2) {
          const int c = jj * 5 + cc2;                    // 32-B chunk 0..19
          unsigned int dw[8];
#pragma unroll
          for (int q = 0; q < 8; ++q) {
            const int s0 = c * 32 + q * 4;
            int lo = __builtin_amdgcn_cvt_pk_fp8_f32(
                slot_val(v, s0 + 0), slot_val(v, s0 + 1), 0, false);
            dw[q] = (unsigned int)__builtin_amdgcn_cvt_pk_fp8_f32(
                slot_val(v, s0 + 2), slot_val(v, s0 + 3), lo, true);
          }
          const int cs = (c & ~3) | ((c & 3) ^ (r & 3));
          unsigned char* dst = As + (size_t)r * KQ + cs * 32;
          uint4 o0; o0.x = dw[0]; o0.y = dw[1]; o0.z = dw[2]; o0.w = dw[3];
          uint4 o1; o1.x = dw[4]; o1.y = dw[5]; o1.z = dw[6]; o1.w = dw[7];
          *(uint4*)dst = o0;
          *(uint4*)(dst + 16) = o1;
        }
      }
    }
  }
  __syncthreads();

#pragma unroll 1
  for (int g = 0; g < 8; ++g) {
    const int mq = ((g * 8 + w) + rot) & 63;             // m-group of 32
    const int m0 = mq * 32;
    const unsigned char* bp0 = Bm8 + (size_t)(m0 +  0 + lrow) * KQ + quad * 32;
    const unsigned char* bp1 = Bm8 + (size_t)(m0 + 16 + lrow) * KQ + quad * 32;
    const int sb0 = (int)sB[m0 +  0 + lrow] * 0x01010101;
    const int sb1 = (int)sB[m0 + 16 + lrow] * 0x01010101;

    floatx4 acc[8][2] = {};                              // [ti][ct]
#pragma unroll
    for (int kk = 0; kk < KSTEPS; ++kk) {
      int8v bf[2];
      {
        uint4 lo = *(const uint4*)(bp0 + kk * 128);
        uint4 hi = *(const uint4*)(bp0 + kk * 128 + 16);
        bf[0][0] = lo.x; bf[0][1] = lo.y; bf[0][2] = lo.z; bf[0][3] = lo.w;
        bf[0][4] = hi.x; bf[0][5] = hi.y; bf[0][6] = hi.z; bf[0][7] = hi.w;
        lo = *(const uint4*)(bp1 + kk * 128);
        hi = *(const uint4*)(bp1 + kk * 128 + 16);
        bf[1][0] = lo.x; bf[1][1] = lo.y; bf[1][2] = lo.z; bf[1][3] = lo.w;
        bf[1][4] = hi.x; bf[1][5] = hi.y; bf[1][6] = hi.z; bf[1][7] = hi.w;
      }
#pragma unroll
      for (int ti = 0; ti < 8; ++ti) {
        const int rr = ti * 16 + lrow;
        const int c = kk * 4 + quad;
        const int cs = (c & ~3) | ((c & 3) ^ (rr & 3));
        const unsigned char* ap = As + (size_t)rr * KQ + cs * 32;
        uint4 lo = *(const uint4*)ap;
        uint4 hi = *(const uint4*)(ap + 16);
        int8v af;
        af[0] = lo.x; af[1] = lo.y; af[2] = lo.z; af[3] = lo.w;
        af[4] = hi.x; af[5] = hi.y; af[6] = hi.z; af[7] = hi.w;
        acc[ti][0] = __builtin_amdgcn_mfma_scale_f32_16x16x128_f8f6f4(
            af, bf[0], acc[ti][0], 0, 0, 0, 0x7F7F7F7F, 0, sb0);
        acc[ti][1] = __builtin_amdgcn_mfma_scale_f32_16x16x128_f8f6f4(
            af, bf[1], acc[ti][1], 0, 0, 0, 0x7F7F7F7F, 0, sb1);
      }
    }

    // screen & emit survivors: acc (= xCx - 2xb) < th[m] = SCREEN - c_m
    const float th0 = th[m0 + lrow];
    const float th1 = th[m0 + 16 + lrow];
#pragma unroll
    for (int ti = 0; ti < 8; ++ti)
#pragma unroll
      for (int ct = 0; ct < 2; ++ct) {
        const float tht = (ct == 0) ? th0 : th1;
#pragma unroll
        for (int r = 0; r < 4; ++r) {
          float Dt = acc[ti][ct][r];
          if (Dt < tht) {
            int gi = i0 + ti * 16 + quad * 4 + r;
            int gm = m0 + ct * 16 + lrow;
            unsigned int idx = atomicAdd(&mcnt[gm], 1u);
            if (idx < MCAP) {
              mlist[(size_t)gm * MCAP + idx] = (unsigned short)gi;
            } else {
              unsigned int fi = atomicAdd(fcount, 1u);
              if (fi < FCAP)
                flist[fi] = ((unsigned int)gi << 11) | (unsigned int)gm;
            }
          }
        }
      }
  }
}

// ---------------------------------------------------------------------------
// Kernel 3: survivor processing (per-m buckets + fallback list).
// ---------------------------------------------------------------------------
__global__ __launch_bounds__(256) void survivor2_kernel(
    const unsigned int* __restrict__ mcnt, const unsigned short* __restrict__ mlist,
    const unsigned int* __restrict__ flist, const unsigned int* __restrict__ fcount,
    const float* __restrict__ x, const float* __restrict__ gamma,
    const float* __restrict__ means, const float* __restrict__ weights,
    double* __restrict__ acc_out) {
  const int blk = blockIdx.x;
  const int t = threadIdx.x;
  if (blk >= MM) {
    unsigned int total = *fcount;
    if (total > FCAP) total = FCAP;
    for (unsigned int idx = (blk - MM) * 256 + t; idx < total; idx += FBLK * 256) {
      unsigned int p = flist[idx];
      int gi = (int)(p >> 11), gm = (int)(p & 2047u);
      double c = survivor_contrib(gm, gamma, means, weights, x + (size_t)gi * DDIM);
      atomicAdd(&acc_out[gi], c);
    }
    return;
  }
  __shared__ float Gt[DDIM][DDIM + 1];
  __shared__ float mu[DDIM];
  const int m = blk;
  unsigned int cnt = mcnt[m];
  if (cnt > MCAP) cnt = MCAP;
  if (cnt == 0) return;
  const float* g = gamma + (size_t)m * DDIM * DDIM;
  for (int l = t; l < DDIM * DDIM; l += 256) Gt[l & 31][l >> 5] = g[l];
  if (t < DDIM) mu[t] = means[m * DDIM + t];
  __syncthreads();
  const float wm = weights[m];
  for (unsigned int s = t; s < cnt; s += 256) {
    int gi = mlist[(size_t)m * MCAP + s];
    float v[DDIM];
#pragma unroll
    for (int q = 0; q < 8; ++q) {
      floatx4 xv = *(const floatx4*)(x + (size_t)gi * DDIM + q * 4);
      v[q * 4 + 0] = xv.x - mu[q * 4 + 0];
      v[q * 4 + 1] = xv.y - mu[q * 4 + 1];
      v[q * 4 + 2] = xv.z - mu[q * 4 + 2];
      v[q * 4 + 3] = xv.w - mu[q * 4 + 3];
    }
    float Dex = 0.f;
#pragma unroll
    for (int e = 0; e < DDIM; ++e) {
      float y = 0.f;
#pragma unroll
      for (int d = 0; d < DDIM; ++d) y += Gt[e][d] * v[d];
      Dex += y * y;
    }
    float e2 = -Dex * 1.44269504088896340736f;
    float kf = floorf(e2);
    float mant = exp2f(e2 - kf);
    atomicAdd(&acc_out[gi], ldexp((double)(wm * mant), (int)kf));
  }
}

__global__ __launch_bounds__(256) void finalize_kernel(
    const double* __restrict__ acc, float* __restrict__ out) {
  int i = blockIdx.x * 256 + threadIdx.x;
  out[i] = (float)acc[i];
}

extern "C" void kernel_launch(void* const* d_in, const int* in_sizes, int n_in,
                              void* d_out, int out_size, void* d_ws, size_t ws_size,
                              hipStream_t stream) {
  (void)in_sizes; (void)n_in; (void)out_size;
  const float* x       = (const float*)d_in[0];   // [N][32]
  const float* gamma   = (const float*)d_in[1];   // [M][32][32]
  const float* means   = (const float*)d_in[2];   // [M][32]
  const float* weights = (const float*)d_in[3];   // [M]

  char* p = (char*)d_ws;
  double* acc          = (double*)p;            p += (size_t)NN * 8;
  unsigned int* fcount = (unsigned int*)p;      p += 16;
  unsigned int* mcnt   = (unsigned int*)p;      p += (size_t)MM * 4;
  unsigned short* mlist= (unsigned short*)p;    p += (size_t)MM * MCAP * 2;
  unsigned int* flist  = (unsigned int*)p;      p += (size_t)FCAP * 4;
  unsigned char* Bm8   = (unsigned char*)p;     p += (size_t)MM * KQ;
  unsigned char* sB    = (unsigned char*)p;     p += (size_t)MM;
  p = (char*)(((uintptr_t)p + 15) & ~(uintptr_t)15);
  float* th            = (float*)p;             p += (size_t)MM * 4;
  const size_t needed = (size_t)(p - (char*)d_ws);
  if (ws_size < needed) return;

  (void)hipFuncSetAttribute((const void*)screen_kernel,
                            hipFuncAttributeMaxDynamicSharedMemorySize,
                            ROWS * KQ);

  hipLaunchKernelGGL(build_b_kernel, dim3(MM), dim3(256), 0, stream,
                     gamma, means, Bm8, sB, th, acc, mcnt, fcount);
  hipLaunchKernelGGL(screen_kernel, dim3(NN / ROWS), dim3(512),
                     ROWS * KQ, stream,
                     x, Bm8, sB, th, mcnt, mlist, flist, fcount);
  hipLaunchKernelGGL(survivor2_kernel, dim3(MM + FBLK), dim3(256), 0, stream,
                     mcnt, mlist, flist, fcount, x, gamma, means, weights, acc);
  hipLaunchKernelGGL(finalize_kernel, dim3(NN / 256), dim3(256), 0, stream,
                     acc, (float*)d_out);
}

// Round 16
// 182.455 us; speedup vs baseline: 2.5158x; 2.5158x over previous
//
#include <hip/hip_runtime.h>
#include <math.h>

// RBF mixture: out[i] = sum_m w_m * exp(-(x_i-mu_m)^T C_m (x_i-mu_m)), C_m = G_m G_m^T
// N=32768, M=2048, D=32.
// Round 16: consolidation of all verified-best components.
//  - screen: r12 verbatim (102us; ROWS=128, 512thr, 147KB LDS A-tile gen'd
//    in-kernel, 32 MFMA/kstep, XOR swizzle, m-rotation). Best of 8 structural
//    variants (r8 TLP-, r14 ILP-, r6/r9 rings, r13 fusion, r11/r15 fp8 all
//    measured worse or neutral).
//  - build_b: r14's (zeroing of acc/mcnt/fcount fused -> no memset dispatch).
//  - survivor2: per-m buckets + fallback list fused (r12).
// 4 dispatches total.

#define NN 32768
#define MM 2048
#define DDIM 32
#define KSYM 576           // 528 triangle + 32 cross + 2 const + 14 pad = 18*32
#define ROWS 128
#define KSTEPS 18
#define SCREEN 120.0f
#define MCAP 2048
#define FCAP 1000000
#define FBLK 64

typedef __attribute__((ext_vector_type(8))) short short8;
typedef __attribute__((ext_vector_type(4))) float floatx4;

__device__ __forceinline__ unsigned int to_bf16(float f) {
  union { float f; unsigned int u; } x; x.f = f;
  return (x.u + 0x7fffu + ((x.u >> 16) & 1u)) >> 16;   // RNE, finite inputs only
}

struct DFTab { unsigned char d[528]; unsigned char f[528]; };
constexpr DFTab make_df() {
  DFTab t{};
  int s = 0;
  for (int d = 0; d < 32; ++d)
    for (int f = d; f < 32; ++f) {
      t.d[s] = (unsigned char)d; t.f[s] = (unsigned char)f; ++s;
    }
  return t;
}
constexpr DFTab DFT = make_df();

__device__ __forceinline__ float slot_val(const float* v, int s) {
  if (s < 528) return v[DFT.d[s]] * v[DFT.f[s]];
  if (s < 560) return v[s - 528];
  if (s < 562) return 1.f;
  return 0.f;
}

__device__ __forceinline__ void slot_df(int s, int* dd, int* ff) {
  int d = 0, b = 0;
  while (b + (DDIM - d) <= s) { b += DDIM - d; ++d; }
  *dd = d; *ff = d + (s - b);
}

// ---------------------------------------------------------------------------
// Kernel 1: bf16 B-matrix [M][KSYM] + fused zeroing of acc/mcnt/fcount.
// ---------------------------------------------------------------------------
__global__ __launch_bounds__(256) void build_b_kernel(
    const float* __restrict__ gamma, const float* __restrict__ means,
    unsigned short* __restrict__ Bm, double* __restrict__ acc,
    unsigned int* __restrict__ mcnt, unsigned int* __restrict__ fcount) {
  __shared__ float G[DDIM][DDIM + 1];
  __shared__ float C[DDIM][DDIM + 1];
  __shared__ float bv[DDIM];
  __shared__ float cc;
  const int m = blockIdx.x;
  const int t = threadIdx.x;
  if (t < 16) acc[m * 16 + t] = 0.0;                 // 2048*16 = 32768 entries
  if (t == 16) mcnt[m] = 0u;
  if (m == 0 && t == 17) *fcount = 0u;
  const float* g = gamma + (size_t)m * DDIM * DDIM;
  for (int l = t; l < DDIM * DDIM; l += 256) G[l >> 5][l & 31] = g[l];
  __syncthreads();
  const float* mu = means + m * DDIM;
  for (int l = t; l < DDIM * DDIM; l += 256) {
    int d = l >> 5, f = l & 31;
    float c = 0.f;
#pragma unroll
    for (int e = 0; e < DDIM; ++e) c += G[d][e] * G[f][e];
    C[d][f] = c;
  }
  __syncthreads();
  if (t < DDIM) {
    float b = 0.f;
#pragma unroll
    for (int f = 0; f < DDIM; ++f) b += C[t][f] * mu[f];
    bv[t] = b;
  }
  __syncthreads();
  if (t == 0) {
    float c = 0.f;
#pragma unroll
    for (int d = 0; d < DDIM; ++d) c += bv[d] * mu[d];
    cc = c;
  }
  __syncthreads();
  unsigned short* brow = Bm + (size_t)m * KSYM;
  for (int s = t; s < KSYM; s += 256) {
    float val;
    if (s < 528) {
      int d, f; slot_df(s, &d, &f);
      val = (d == f) ? C[d][d] : 2.f * C[d][f];
    } else if (s < 560) {
      val = -2.f * bv[s - 528];
    } else if (s == 560) {
      val = cc;
    } else if (s == 561) {
      unsigned int hi = to_bf16(cc);
      union { unsigned int u; float f; } xh; xh.u = hi << 16;
      val = cc - xh.f;
    } else {
      val = 0.f;
    }
    brow[s] = (unsigned short)to_bf16(val);
  }
}

// ---------------------------------------------------------------------------
// Exact scalar path (fallback list only).
// ---------------------------------------------------------------------------
__device__ __noinline__ double survivor_contrib(
    int m, const float* __restrict__ gamma, const float* __restrict__ means,
    const float* __restrict__ weights, const float* __restrict__ xrow) {
  const float* mu = means + m * DDIM;
  float v[DDIM];
#pragma unroll
  for (int d = 0; d < DDIM; ++d) v[d] = xrow[d] - mu[d];
  const float* g = gamma + (size_t)m * DDIM * DDIM;
  float Dex = 0.f;
  for (int e = 0; e < DDIM; ++e) {
    float y = 0.f;
#pragma unroll
    for (int d = 0; d < DDIM; ++d) y += g[d * DDIM + e] * v[d];
    Dex += y * y;
  }
  float e2 = -Dex * 1.44269504088896340736f;
  float kf = floorf(e2);
  float mant = exp2f(e2 - kf);
  return ldexp((double)(weights[m] * mant), (int)kf);
}

// ---------------------------------------------------------------------------
// Kernel 2: bf16 MFMA screen (r12 verbatim). 512 threads (8 waves), 128-row
// A-tile generated in-kernel into 147 KB dynamic LDS (XOR chunk swizzle;
// 0 conflicts r3-r14). 1 block/CU, 2 waves/SIMD (LDS-bound). Per kstep:
// 4 B-loads + 8 ds_read_b128 + 32 MFMA. Wave w sweeps m-quads
// ((g*8+w)+rot)&31, g=0..3, rot=blockIdx&31 (L2 spread).
// Frag layout (m89/m97): A/B [row=lane&15][k=quad*8+j]; C/D col=lane&15,
// row=quad*4+reg. Survivors -> per-m bucket lists; overflow -> flat list.
// ---------------------------------------------------------------------------
__global__ __launch_bounds__(512, 1) void screen_kernel(
    const float* __restrict__ x, const unsigned short* __restrict__ Bm,
    unsigned int* __restrict__ mcnt, unsigned short* __restrict__ mlist,
    unsigned int* __restrict__ flist, unsigned int* __restrict__ fcount) {
  extern __shared__ __align__(16) unsigned short As[];   // ROWS * KSYM
  const int t = threadIdx.x;
  const int i0 = blockIdx.x * ROWS;
  const int lane = t & 63, w = t >> 6;                   // w in [0,8)
  const int lrow = lane & 15, quad = lane >> 4;
  const int rot = blockIdx.x & 31;

  // ---- generate A tile into swizzled LDS: row r (128), chunk-quarter j (4) ----
  {
    const int r = t >> 2, j = t & 3;
    float v[DDIM];
#pragma unroll
    for (int q = 0; q < 8; ++q)
      *(floatx4*)&v[q * 4] = *(const floatx4*)(x + (size_t)(i0 + r) * DDIM + q * 4);
#pragma unroll
    for (int jj = 0; jj < 4; ++jj) {
      if (j == jj) {
#pragma unroll
        for (int cc2 = 0; cc2 < 18; ++cc2) {
          const int c = jj * 18 + cc2;                   // 16B chunk index 0..71
          unsigned int uu[4];
#pragma unroll
          for (int q = 0; q < 4; ++q) {
            const int s0 = c * 8 + q * 2;
            uu[q] = to_bf16(slot_val(v, s0)) | (to_bf16(slot_val(v, s0 + 1)) << 16);
          }
          const int cs = (c & ~7) | ((c & 7) ^ (r & 7));
          uint4 o; o.x = uu[0]; o.y = uu[1]; o.z = uu[2]; o.w = uu[3];
          *(uint4*)&As[r * KSYM + cs * 8] = o;
        }
      }
    }
  }
  __syncthreads();

#pragma unroll 1
  for (int g = 0; g < 4; ++g) {
    const int mq = ((g * 8 + w) + rot) & 31;
    const int m0 = mq * 64;
    const unsigned short* bb0 = Bm + (size_t)(m0 +  0 + lrow) * KSYM + quad * 8;
    const unsigned short* bb1 = Bm + (size_t)(m0 + 16 + lrow) * KSYM + quad * 8;
    const unsigned short* bb2 = Bm + (size_t)(m0 + 32 + lrow) * KSYM + quad * 8;
    const unsigned short* bb3 = Bm + (size_t)(m0 + 48 + lrow) * KSYM + quad * 8;

    floatx4 acc[8][4] = {};                              // [ti][mj]
#pragma unroll
    for (int kk = 0; kk < KSTEPS; ++kk) {
      short8 bf[4];
      bf[0] = *(const short8*)(bb0 + kk * 32);
      bf[1] = *(const short8*)(bb1 + kk * 32);
      bf[2] = *(const short8*)(bb2 + kk * 32);
      bf[3] = *(const short8*)(bb3 + kk * 32);
      short8 af[8];
#pragma unroll
      for (int ti = 0; ti < 8; ++ti) {
        int rr = ti * 16 + lrow;
        int c = kk * 4 + quad;
        int cs = (c & ~7) | ((c & 7) ^ (rr & 7));
        af[ti] = *(const short8*)&As[rr * KSYM + cs * 8];
      }
#pragma unroll
      for (int ti = 0; ti < 8; ++ti)
#pragma unroll
        for (int mj = 0; mj < 4; ++mj)
          acc[ti][mj] = __builtin_amdgcn_mfma_f32_16x16x32_bf16(
              af[ti], bf[mj], acc[ti][mj], 0, 0, 0);
    }

    // screen & emit survivors (rare) into per-m buckets
#pragma unroll
    for (int ti = 0; ti < 8; ++ti)
#pragma unroll
      for (int mj = 0; mj < 4; ++mj)
#pragma unroll
        for (int r = 0; r < 4; ++r) {
          float Dt = acc[ti][mj][r];
          if (Dt < SCREEN) {
            int gi = i0 + ti * 16 + quad * 4 + r;
            int gm = m0 + mj * 16 + lrow;
            unsigned int idx = atomicAdd(&mcnt[gm], 1u);
            if (idx < MCAP) {
              mlist[(size_t)gm * MCAP + idx] = (unsigned short)gi;
            } else {
              unsigned int fi = atomicAdd(fcount, 1u);
              if (fi < FCAP)
                flist[fi] = ((unsigned int)gi << 11) | (unsigned int)gm;
            }
          }
        }
  }
}

// ---------------------------------------------------------------------------
// Kernel 3: survivor processing (per-m buckets + fallback list).
// ---------------------------------------------------------------------------
__global__ __launch_bounds__(256) void survivor2_kernel(
    const unsigned int* __restrict__ mcnt, const unsigned short* __restrict__ mlist,
    const unsigned int* __restrict__ flist, const unsigned int* __restrict__ fcount,
    const float* __restrict__ x, const float* __restrict__ gamma,
    const float* __restrict__ means, const float* __restrict__ weights,
    double* __restrict__ acc_out) {
  const int blk = blockIdx.x;
  const int t = threadIdx.x;
  if (blk >= MM) {
    unsigned int total = *fcount;
    if (total > FCAP) total = FCAP;
    for (unsigned int idx = (blk - MM) * 256 + t; idx < total; idx += FBLK * 256) {
      unsigned int p = flist[idx];
      int gi = (int)(p >> 11), gm = (int)(p & 2047u);
      double c = survivor_contrib(gm, gamma, means, weights, x + (size_t)gi * DDIM);
      atomicAdd(&acc_out[gi], c);
    }
    return;
  }
  __shared__ float Gt[DDIM][DDIM + 1];
  __shared__ float mu[DDIM];
  const int m = blk;
  unsigned int cnt = mcnt[m];
  if (cnt > MCAP) cnt = MCAP;
  if (cnt == 0) return;
  const float* g = gamma + (size_t)m * DDIM * DDIM;
  for (int l = t; l < DDIM * DDIM; l += 256) Gt[l & 31][l >> 5] = g[l];
  if (t < DDIM) mu[t] = means[m * DDIM + t];
  __syncthreads();
  const float wm = weights[m];
  for (unsigned int s = t; s < cnt; s += 256) {
    int gi = mlist[(size_t)m * MCAP + s];
    float v[DDIM];
#pragma unroll
    for (int q = 0; q < 8; ++q) {
      floatx4 xv = *(const floatx4*)(x + (size_t)gi * DDIM + q * 4);
      v[q * 4 + 0] = xv.x - mu[q * 4 + 0];
      v[q * 4 + 1] = xv.y - mu[q * 4 + 1];
      v[q * 4 + 2] = xv.z - mu[q * 4 + 2];
      v[q * 4 + 3] = xv.w - mu[q * 4 + 3];
    }
    float Dex = 0.f;
#pragma unroll
    for (int e = 0; e < DDIM; ++e) {
      float y = 0.f;
#pragma unroll
      for (int d = 0; d < DDIM; ++d) y += Gt[e][d] * v[d];
      Dex += y * y;
    }
    float e2 = -Dex * 1.44269504088896340736f;
    float kf = floorf(e2);
    float mant = exp2f(e2 - kf);
    atomicAdd(&acc_out[gi], ldexp((double)(wm * mant), (int)kf));
  }
}

__global__ __launch_bounds__(256) void finalize_kernel(
    const double* __restrict__ acc, float* __restrict__ out) {
  int i = blockIdx.x * 256 + threadIdx.x;
  out[i] = (float)acc[i];
}

extern "C" void kernel_launch(void* const* d_in, const int* in_sizes, int n_in,
                              void* d_out, int out_size, void* d_ws, size_t ws_size,
                              hipStream_t stream) {
  (void)in_sizes; (void)n_in; (void)out_size;
  const float* x       = (const float*)d_in[0];   // [N][32]
  const float* gamma   = (const float*)d_in[1];   // [M][32][32]
  const float* means   = (const float*)d_in[2];   // [M][32]
  const float* weights = (const float*)d_in[3];   // [M]

  char* p = (char*)d_ws;
  double* acc          = (double*)p;            p += (size_t)NN * 8;
  unsigned int* fcount = (unsigned int*)p;      p += 16;
  unsigned int* mcnt   = (unsigned int*)p;      p += (size_t)MM * 4;
  unsigned short* mlist= (unsigned short*)p;    p += (size_t)MM * MCAP * 2;
  unsigned int* flist  = (unsigned int*)p;      p += (size_t)FCAP * 4;
  unsigned short* Bm   = (unsigned short*)p;    p += (size_t)MM * KSYM * 2;
  const size_t needed = (size_t)(p - (char*)d_ws);
  if (ws_size < needed) return;

  (void)hipFuncSetAttribute((const void*)screen_kernel,
                            hipFuncAttributeMaxDynamicSharedMemorySize,
                            ROWS * KSYM * 2);

  hipLaunchKernelGGL(build_b_kernel, dim3(MM), dim3(256), 0, stream,
                     gamma, means, Bm, acc, mcnt, fcount);
  hipLaunchKernelGGL(screen_kernel, dim3(NN / ROWS), dim3(512),
                     ROWS * KSYM * 2, stream,
                     x, Bm, mcnt, mlist, flist, fcount);
  hipLaunchKernelGGL(survivor2_kernel, dim3(MM + FBLK), dim3(256), 0, stream,
                     mcnt, mlist, flist, fcount, x, gamma, means, weights, acc);
  hipLaunchKernelGGL(finalize_kernel, dim3(NN / 256), dim3(256), 0, stream,
                     acc, (float*)d_out);
}